// Round 5
// baseline (176.423 us; speedup 1.0000x reference)
//
#include <hip/hip_runtime.h>
#include <hip/hip_fp16.h>
#include <math.h>

#define N_NODES 50000
#define N_REL   1000
#define D       128
#define NNZ     800000

#define RB    64                   // rows per bin (6-bit rowlocal -> 32-bit edge pack)
#define NBIN  782                  // ceil(50000/64)
#define CAP   1280                 // slots/bin: mean 1023, sigma ~32 -> 8-sigma margin
#define NBK1  768                  // k1 blocks: 3/CU, 24 waves/CU
#define K1T   512
#define PBT   512
#define PE    3                    // ceil(CAP/PBT) staged edges/thread in place

// ===== K1: scores + f32->f16 convert + direct-scatter bin partition ===============
// Edge pack (u32): col:16 | rel:10 | rowlocal:6. Bin cursor writes advance
// monotonically -> ~782 hot lines (50KB) stay in L2 and write-merge; no LDS sort.
__global__ void __launch_bounds__(K1T)
k1_kernel(const int* __restrict__ rows, const int* __restrict__ cols,
          const int* __restrict__ rel, const float* __restrict__ dual,
          const float* __restrict__ conv_w, const float* __restrict__ conv_b,
          const float* __restrict__ inlayer, float* __restrict__ exp_scores,
          unsigned* __restrict__ bincur, unsigned* __restrict__ binbuf,
          __half2* __restrict__ hinl) {
    int t = threadIdx.x;
    int gtid = blockIdx.x * K1T + t;
    int lane = t & 63;

    // --- relation scores: one wave per relation (first 1000 waves of the grid) ---
    int wid = gtid >> 6;
    if (wid < N_REL) {
        const float* row = dual + (long)wid * D;
        float s = row[lane] * conv_w[lane] + row[lane + 64] * conv_w[lane + 64];
        #pragma unroll
        for (int off = 32; off > 0; off >>= 1) s += __shfl_down(s, off);
        if (lane == 0) {
            float v = s + conv_b[0];
            v = (v >= 0.f) ? v : 0.01f * v;        // leaky_relu
            exp_scores[wid] = expf(v);             // scores ~N(0,1): safe
        }
    }

    // --- f32 -> f16 convert (grid-stride float4, coalesced) ---
    const float4* src4 = (const float4*)inlayer;
    uint2* dst2 = (uint2*)hinl;
    for (int i = gtid; i < N_NODES * D / 4; i += NBK1 * K1T) {
        float4 f = src4[i];
        __half2 h0 = __floats2half2_rn(f.x, f.y);
        __half2 h1 = __floats2half2_rn(f.z, f.w);
        uint2 o; o.x = *(unsigned*)&h0; o.y = *(unsigned*)&h1;
        dst2[i] = o;
    }

    // --- direct-scatter partition: 1 atomic + 1 store per edge, no barriers ---
    const int4* r4 = (const int4*)rows;
    const int4* c4 = (const int4*)cols;
    const int4* q4 = (const int4*)rel;
    for (int j = gtid; j < NNZ / 4; j += NBK1 * K1T) {
        int4 rr = r4[j]; int4 cc = c4[j]; int4 qq = q4[j];
        #pragma unroll
        for (int k = 0; k < 4; ++k) {
            int r = (k == 0) ? rr.x : (k == 1) ? rr.y : (k == 2) ? rr.z : rr.w;
            int c = (k == 0) ? cc.x : (k == 1) ? cc.y : (k == 2) ? cc.z : cc.w;
            int q = (k == 0) ? qq.x : (k == 1) ? qq.y : (k == 2) ? qq.z : qq.w;
            int b = r >> 6;
            unsigned pk = (unsigned)c | ((unsigned)q << 16)
                        | ((unsigned)(r & 63) << 26);
            unsigned pos = atomicAdd(&bincur[b * 16], 1u);  // padded: 1 cursor/line
            if (pos < CAP)
                binbuf[(unsigned)b * CAP + pos] = pk;
        }
    }
}

// ===== K2: per-bin place — single-pass reg staging; writes starts + 4B packs =====
__global__ void __launch_bounds__(PBT)
place_kernel(const unsigned* __restrict__ bincur,
             const unsigned* __restrict__ binbuf,
             const float* __restrict__ exp_scores,
             unsigned* __restrict__ starts, unsigned* __restrict__ bpack,
             float* __restrict__ denom) {
    __shared__ unsigned cnt[RB], cur[RB], ex[RB];
    __shared__ unsigned wsum[8];
    __shared__ float    rpart[8];
    __shared__ unsigned sh_binbase;
    int t = threadIdx.x, lane = t & 63, w = t >> 6;
    int b = blockIdx.x;
    int rlo = b * RB;
    unsigned nb = bincur[b * 16]; if (nb > CAP) nb = CAP;
    const unsigned* bb = binbuf + (unsigned)b * CAP;

    if (t < RB) { cnt[t] = 0; cur[t] = 0; }
    __syncthreads();

    // stage edges in registers (static indexing) + LDS row histogram
    unsigned epk[PE];
    #pragma unroll
    for (int k = 0; k < PE; ++k) {
        int e = t + k * PBT;
        if (e < (int)nb) {
            unsigned pk = bb[e];
            epk[k] = pk;
            atomicAdd(&cnt[pk >> 26], 1u);
        }
    }

    // bin base = sum of earlier bins' counts (grid-stride over b, 512-thread reduce)
    unsigned bv = 0;
    for (int i = t; i < b; i += PBT) bv += min(bincur[i * 16], (unsigned)CAP);
    #pragma unroll
    for (int off = 32; off > 0; off >>= 1) bv += __shfl_down(bv, off);
    if (lane == 0) wsum[w] = bv;
    __syncthreads();                        // also orders cnt[] histogram
    if (t == 0) {
        unsigned s = 0;
        #pragma unroll
        for (int k = 0; k < 8; ++k) s += wsum[k];
        sh_binbase = s;
    }

    // wave 0: exclusive scan of the 64 row counts
    if (t < 64) {
        unsigned c0 = cnt[t];
        unsigned v = c0;
        #pragma unroll
        for (int off = 1; off < 64; off <<= 1) {
            unsigned y = __shfl_up(v, off);
            if (lane >= off) v += y;
        }
        ex[t] = v - c0;
    }
    __syncthreads();
    unsigned base = sh_binbase;
    if (t < RB && rlo + t <= N_NODES)
        starts[rlo + t] = base + ex[t];     // starts[50000] lands at t=16 of bin 781

    // place edges from registers: LDS cursors; 4B writes in L2-hot window
    float dsum = 0.f;
    #pragma unroll
    for (int k = 0; k < PE; ++k) {
        int e = t + k * PBT;
        if (e < (int)nb) {
            unsigned pk = epk[k];
            int r = (int)(pk >> 26);
            unsigned rank = atomicAdd(&cur[r], 1u);
            bpack[base + ex[r] + rank] = pk & 0x3FFFFFFu;   // col | rel<<16
            dsum += exp_scores[(pk >> 16) & 0x3FFu];
        }
    }
    #pragma unroll
    for (int off = 32; off > 0; off >>= 1) dsum += __shfl_down(dsum, off);
    if (lane == 0) rpart[w] = dsum;
    __syncthreads();
    if (t == 0) {
        float s = 0.f;
        #pragma unroll
        for (int k = 0; k < 8; ++k) s += rpart[k];
        atomicAdd(denom, s);
    }
}

// ===== K3: gather — fp16 rows, 16 lanes/row, 4 rows per load; /denom epilogue =====
__global__ void gather_kernel(const unsigned* __restrict__ starts,
                              const unsigned* __restrict__ bpack,
                              const float* __restrict__ exp_scores,
                              const __half2* __restrict__ hinl,
                              const float* __restrict__ denom,
                              float* __restrict__ out) {
    int node = blockIdx.x * (blockDim.x >> 6) + (threadIdx.x >> 6);
    int lane = threadIdx.x & 63;
    if (node >= N_NODES) return;
    int s = (int)starts[node];
    int e = (int)starts[node + 1];
    int quad = lane >> 4;                  // which of 4 rows per load
    int l16  = lane & 15;                  // 8-dim group within row
    float a0=0.f,a1=0.f,a2=0.f,a3=0.f,a4=0.f,a5=0.f,a6=0.f,a7=0.f;
    for (int base = s; base < e; base += 64) {
        int rem = e - base; if (rem > 64) rem = 64;
        int px = 0, py = 0;
        if (lane < rem) {
            unsigned pk = bpack[base + lane];          // coalesced 256B / 64 edges
            px = (int)(pk & 0xFFFFu);
            py = __float_as_int(exp_scores[pk >> 16]); // 4KB table: L1-resident
        }
        for (int j = 0; j < rem; j += 16) {
            #pragma unroll
            for (int k = 0; k < 16; k += 4) {
                if (j + k < rem) {         // wave-uniform guard
                    int idx = j + k + quad;
                    int   c = __shfl(px, idx);           // 0 beyond rem -> w=0
                    float wv = __int_as_float(__shfl(py, idx));
                    const __half2* hp = hinl + (long)c * (D / 2) + l16 * 4;
                    uint4 hv = *(const uint4*)hp;        // 8 halves (16B)
                    float2 f0 = __half22float2(*(const __half2*)&hv.x);
                    float2 f1 = __half22float2(*(const __half2*)&hv.y);
                    float2 f2 = __half22float2(*(const __half2*)&hv.z);
                    float2 f3 = __half22float2(*(const __half2*)&hv.w);
                    a0 += wv * f0.x; a1 += wv * f0.y;
                    a2 += wv * f1.x; a3 += wv * f1.y;
                    a4 += wv * f2.x; a5 += wv * f2.y;
                    a6 += wv * f3.x; a7 += wv * f3.y;
                }
            }
        }
    }
    #define COMB(x) x += __shfl(x, lane ^ 16); x += __shfl(x, lane ^ 32);
    COMB(a0) COMB(a1) COMB(a2) COMB(a3) COMB(a4) COMB(a5) COMB(a6) COMB(a7)
    #undef COMB
    if (lane < 32) {                       // 32 lanes cover the 512B row store
        float inv = 1.0f / *denom;         // normalization deferred to epilogue
        float4 v;
        int hi = (lane >> 4) & 1;
        if (hi) { v.x = a4*inv; v.y = a5*inv; v.z = a6*inv; v.w = a7*inv; }
        else    { v.x = a0*inv; v.y = a1*inv; v.z = a2*inv; v.w = a3*inv; }
        *(float4*)(out + (long)node * D + l16 * 8 + hi * 4) = v;
    }
}

extern "C" void kernel_launch(void* const* d_in, const int* in_sizes, int n_in,
                              void* d_out, int out_size, void* d_ws, size_t ws_size,
                              hipStream_t stream) {
    const float* inlayer  = (const float*)d_in[0];
    const float* dual     = (const float*)d_in[1];
    const float* conv_w   = (const float*)d_in[2];
    const float* conv_b   = (const float*)d_in[3];
    const int*   edge_idx = (const int*)d_in[4];   // [2, NNZ]: rows then cols
    const int*   edge_rel = (const int*)d_in[5];
    float* out = (float*)d_out;
    const int* rows = edge_idx;
    const int* cols = edge_idx + NNZ;

    // workspace layout (16B aligned) — total ~20.3 MB
    char* ws = (char*)d_ws;
    float*    exp_scores = (float*)   (ws);                 // 4 KB
    float*    denom      = (float*)   (ws + 4096);          // 4 B
    unsigned* bincur     = (unsigned*)(ws + 8192);          // 782*16 u32 (line-padded, 50 KB)
    unsigned* starts     = (unsigned*)(ws + 65536);         // 50001 u32
    unsigned* binbuf     = (unsigned*)(ws + 266240);        // 782*1280*4 = 4.0 MB
    unsigned* bpack      = (unsigned*)(ws + 4270080);       // 3.2 MB
    __half2*  hinl       = (__half2*) (ws + 7470080);       // 12.8 MB

    // zero denom + bincur in one ~55 KB fill
    hipMemsetAsync(ws + 4096, 0, 4096 + NBIN * 64, stream);

    k1_kernel<<<NBK1, K1T, 0, stream>>>(rows, cols, edge_rel, dual, conv_w, conv_b,
                                        inlayer, exp_scores, bincur, binbuf, hinl);
    place_kernel<<<NBIN, PBT, 0, stream>>>(bincur, binbuf, exp_scores,
                                           starts, bpack, denom);
    int grid = (N_NODES + 3) / 4;   // 4 waves/block, one node per wave
    gather_kernel<<<grid, 256, 0, stream>>>(starts, bpack, exp_scores,
                                            hinl, denom, out);
}

// Round 6
// 148.769 us; speedup vs baseline: 1.1859x; 1.1859x over previous
//
#include <hip/hip_runtime.h>
#include <hip/hip_fp16.h>
#include <math.h>

#define N_NODES 50000
#define N_REL   1000
#define D       128
#define NNZ     800000

#define RB    512                  // rows per bin (coarse: long k1 write runs)
#define NBIN  98                   // ceil(50000/512)
#define CAP   10240                // slots/bin: mean 8184, sigma ~90
#define SUBR  128                  // rows per place sub-block
#define CH    2048                 // edges per partition chunk
#define NCH   ((NNZ + CH - 1) / CH)   // 391 chunks/blocks
#define K1T   512
#define K1E   (CH / K1T)           // 4 edges/thread
#define PBT   512

// ===== K1: scores + f32->f16 convert + LDS-sorted bin partition (full-line runs) =====
// Edge pack (u64): col:16 | rel:10 | rowlocal:9. 98 bins -> ~21-edge (168B) runs.
__global__ void __launch_bounds__(K1T)
k1_kernel(const int* __restrict__ rows, const int* __restrict__ cols,
          const int* __restrict__ rel, const float* __restrict__ dual,
          const float* __restrict__ conv_w, const float* __restrict__ conv_b,
          const float* __restrict__ inlayer, float* __restrict__ exp_scores,
          unsigned* __restrict__ bincur, unsigned long long* __restrict__ binbuf,
          __half2* __restrict__ hinl) {
    __shared__ unsigned long long sbuf[CH];     // 16 KB chunk staging (bin-sorted)
    __shared__ unsigned char sbin[CH];          // 2 KB per-slot bin id (98 < 256)
    __shared__ unsigned lcnt[NBIN], lstart[NBIN], lgb[NBIN];
    __shared__ unsigned w0sum;
    int t = threadIdx.x;
    int gtid = blockIdx.x * K1T + t;
    int lane = t & 63;

    // --- relation scores: one wave per relation (first 1000 waves of the grid) ---
    int wid = gtid >> 6;
    if (wid < N_REL) {
        const float* row = dual + (long)wid * D;
        float s = row[lane] * conv_w[lane] + row[lane + 64] * conv_w[lane + 64];
        #pragma unroll
        for (int off = 32; off > 0; off >>= 1) s += __shfl_down(s, off);
        if (lane == 0) {
            float v = s + conv_b[0];
            v = (v >= 0.f) ? v : 0.01f * v;        // leaky_relu
            exp_scores[wid] = expf(v);             // scores ~N(0,1): safe
        }
    }

    // --- f32 -> f16 convert (grid-stride float4, coalesced) ---
    const float4* src4 = (const float4*)inlayer;
    uint2* dst2 = (uint2*)hinl;
    for (int i = gtid; i < N_NODES * D / 4; i += NCH * K1T) {
        float4 f = src4[i];
        __half2 h0 = __floats2half2_rn(f.x, f.y);
        __half2 h1 = __floats2half2_rn(f.z, f.w);
        uint2 o; o.x = *(unsigned*)&h0; o.y = *(unsigned*)&h1;
        dst2[i] = o;
    }

    // --- partition this block's 2048-edge chunk ---
    if (t < NBIN) lcnt[t] = 0;
    __syncthreads();

    int n = NNZ - blockIdx.x * CH; if (n > CH) n = CH;   // tail = 1280 (mult of 4)
    int base4 = blockIdx.x * (CH / 4);

    int       ebin[K1E];
    unsigned  erank[K1E];
    unsigned long long epack[K1E];
    bool has = (4 * t < n);
    int4 rr, cc, qq;
    if (has) {
        rr = ((const int4*)rows)[base4 + t];
        cc = ((const int4*)cols)[base4 + t];
        qq = ((const int4*)rel)[base4 + t];
    }
    #pragma unroll
    for (int k = 0; k < K1E; ++k) {
        if (has) {
            int r = (k == 0) ? rr.x : (k == 1) ? rr.y : (k == 2) ? rr.z : rr.w;
            int c = (k == 0) ? cc.x : (k == 1) ? cc.y : (k == 2) ? cc.z : cc.w;
            int q = (k == 0) ? qq.x : (k == 1) ? qq.y : (k == 2) ? qq.z : qq.w;
            int b = r >> 9;
            epack[k] = (unsigned long long)(unsigned)c
                     | ((unsigned long long)(unsigned)q << 16)
                     | ((unsigned long long)(unsigned)(r & 511) << 26);
            ebin[k] = b;
            erank[k] = atomicAdd(&lcnt[b], 1u);
        } else ebin[k] = -1;
    }
    __syncthreads();

    // exclusive scan of 98 bin counts (2 waves) + reserve global runs
    unsigned v = (t < NBIN) ? lcnt[t] : 0u;
    if (t < 128) {
        #pragma unroll
        for (int off = 1; off < 64; off <<= 1) {
            unsigned y = __shfl_up(v, off);
            if (lane >= off) v += y;
        }
        if (t == 63) w0sum = v;
    }
    __syncthreads();
    if (t >= 64 && t < 128) v += w0sum;
    if (t < NBIN) {
        lstart[t] = v - lcnt[t];
        lgb[t] = atomicAdd(&bincur[t * 16], lcnt[t]);   // padded cursors: 1/line
    }
    __syncthreads();

    // LDS scatter into bin-sorted order
    #pragma unroll
    for (int k = 0; k < K1E; ++k) {
        if (ebin[k] >= 0) {
            unsigned p = lstart[ebin[k]] + erank[k];
            sbuf[p] = epack[k];
            sbin[p] = (unsigned char)ebin[k];
        }
    }
    __syncthreads();

    // coalesced run writes: ~21-edge (168B) runs -> mostly full 64B lines
    #pragma unroll
    for (int k = 0; k < K1E; ++k) {
        int j = k * K1T + t;
        if (j < n) {
            int b = sbin[j];
            unsigned slot = lgb[b] + (unsigned)j - lstart[b];
            if (slot < CAP)
                binbuf[(unsigned long long)b * CAP + slot] = sbuf[j];
        }
    }
}

// ===== K2: place — 4 sub-blocks per bin, each owns 128 rows; 2 cached passes =====
__global__ void __launch_bounds__(PBT)
place_kernel(const unsigned* __restrict__ bincur,
             const unsigned long long* __restrict__ binbuf,
             const float* __restrict__ exp_scores,
             unsigned* __restrict__ starts, unsigned* __restrict__ bpack,
             float* __restrict__ denom) {
    __shared__ unsigned cnt[SUBR], cur[SUBR], ex[SUBR];
    __shared__ unsigned wsum[8], bsum[8];
    __shared__ float    rpart[8];
    __shared__ unsigned sh_base;
    int t = threadIdx.x, lane = t & 63, w = t >> 6;
    int b   = blockIdx.x >> 2;             // bin 0..97
    int sub = blockIdx.x & 3;              // row quarter within bin
    int rlo = b * RB + sub * SUBR;
    unsigned nb = bincur[b * 16]; if (nb > CAP) nb = CAP;
    const unsigned long long* bb = binbuf + (unsigned long long)b * CAP;

    if (t < SUBR) { cnt[t] = 0; cur[t] = 0; }
    __syncthreads();

    // pass 1: histogram own-range rows + count edges below own range
    unsigned below = 0;
    for (int e = t; e < (int)nb; e += PBT) {
        unsigned u = (unsigned)(bb[e] >> 26);          // rowlocal 0..511
        unsigned us = u >> 7;                          // sub-range 0..3
        if (us == (unsigned)sub) atomicAdd(&cnt[u & 127], 1u);
        below += (us < (unsigned)sub) ? 1u : 0u;
    }

    // block base = sum of earlier bins' counts + below-count (one reduce pass)
    unsigned bv = (t < b) ? min(bincur[t * 16], (unsigned)CAP) : 0u;
    #pragma unroll
    for (int off = 32; off > 0; off >>= 1) {
        bv    += __shfl_down(bv, off);
        below += __shfl_down(below, off);
    }
    if (lane == 0) { wsum[w] = bv; bsum[w] = below; }
    __syncthreads();                        // also orders cnt[] histogram
    if (t == 0) {
        unsigned s = 0;
        #pragma unroll
        for (int k = 0; k < 8; ++k) s += wsum[k] + bsum[k];
        sh_base = s;
    }
    __syncthreads();

    // exclusive scan of the 128 own-range row counts (8-wave scan, zeros beyond)
    unsigned c0 = (t < SUBR) ? cnt[t] : 0u;
    unsigned v = c0;
    #pragma unroll
    for (int off = 1; off < 64; off <<= 1) {
        unsigned y = __shfl_up(v, off);
        if (lane >= off) v += y;
    }
    if (lane == 63) wsum[w] = v;
    __syncthreads();
    if (t == 0) {
        unsigned acc = 0;
        #pragma unroll
        for (int k = 0; k < 8; ++k) { unsigned tmp = wsum[k]; wsum[k] = acc; acc += tmp; }
    }
    __syncthreads();
    unsigned base = sh_base;
    if (t < SUBR) ex[t] = wsum[w] + (v - c0);
    if (t < SUBR && rlo + t <= N_NODES)
        starts[rlo + t] = base + wsum[w] + (v - c0);   // sentinel at 50000 covered
    __syncthreads();

    // pass 2 (L2-hot re-read): place own-range edges; 4B writes in 8KB window
    float dsum = 0.f;
    for (int e = t; e < (int)nb; e += PBT) {
        unsigned long long pk = bb[e];
        unsigned u = (unsigned)(pk >> 26);
        if ((u >> 7) == (unsigned)sub) {
            int r = (int)(u & 127);
            unsigned rank = atomicAdd(&cur[r], 1u);
            unsigned lp = (unsigned)(pk & 0x3FFFFFFULL);   // col | rel<<16
            bpack[base + ex[r] + rank] = lp;
            dsum += exp_scores[lp >> 16];
        }
    }
    #pragma unroll
    for (int off = 32; off > 0; off >>= 1) dsum += __shfl_down(dsum, off);
    if (lane == 0) rpart[w] = dsum;
    __syncthreads();
    if (t == 0) {
        float s = 0.f;
        #pragma unroll
        for (int k = 0; k < 8; ++k) s += rpart[k];
        atomicAdd(denom, s);
    }
}

// ===== K3: gather — fp16 rows, 16 lanes/row, 4 rows per load; /denom epilogue =====
__global__ void gather_kernel(const unsigned* __restrict__ starts,
                              const unsigned* __restrict__ bpack,
                              const float* __restrict__ exp_scores,
                              const __half2* __restrict__ hinl,
                              const float* __restrict__ denom,
                              float* __restrict__ out) {
    int node = blockIdx.x * (blockDim.x >> 6) + (threadIdx.x >> 6);
    int lane = threadIdx.x & 63;
    if (node >= N_NODES) return;
    int s = (int)starts[node];
    int e = (int)starts[node + 1];
    int quad = lane >> 4;                  // which of 4 rows per load
    int l16  = lane & 15;                  // 8-dim group within row
    float a0=0.f,a1=0.f,a2=0.f,a3=0.f,a4=0.f,a5=0.f,a6=0.f,a7=0.f;
    for (int base = s; base < e; base += 64) {
        int rem = e - base; if (rem > 64) rem = 64;
        int px = 0, py = 0;
        if (lane < rem) {
            unsigned pk = bpack[base + lane];          // coalesced 256B / 64 edges
            px = (int)(pk & 0xFFFFu);
            py = __float_as_int(exp_scores[pk >> 16]); // 4KB table: L1-resident
        }
        for (int j = 0; j < rem; j += 16) {
            #pragma unroll
            for (int k = 0; k < 16; k += 4) {
                if (j + k < rem) {         // wave-uniform guard
                    int idx = j + k + quad;
                    int   c = __shfl(px, idx);           // 0 beyond rem -> w=0
                    float wv = __int_as_float(__shfl(py, idx));
                    const __half2* hp = hinl + (long)c * (D / 2) + l16 * 4;
                    uint4 hv = *(const uint4*)hp;        // 8 halves (16B)
                    float2 f0 = __half22float2(*(const __half2*)&hv.x);
                    float2 f1 = __half22float2(*(const __half2*)&hv.y);
                    float2 f2 = __half22float2(*(const __half2*)&hv.z);
                    float2 f3 = __half22float2(*(const __half2*)&hv.w);
                    a0 += wv * f0.x; a1 += wv * f0.y;
                    a2 += wv * f1.x; a3 += wv * f1.y;
                    a4 += wv * f2.x; a5 += wv * f2.y;
                    a6 += wv * f3.x; a7 += wv * f3.y;
                }
            }
        }
    }
    #define COMB(x) x += __shfl(x, lane ^ 16); x += __shfl(x, lane ^ 32);
    COMB(a0) COMB(a1) COMB(a2) COMB(a3) COMB(a4) COMB(a5) COMB(a6) COMB(a7)
    #undef COMB
    if (lane < 32) {                       // 32 lanes cover the 512B row store
        float inv = 1.0f / *denom;         // normalization deferred to epilogue
        float4 v;
        int hi = (lane >> 4) & 1;
        if (hi) { v.x = a4*inv; v.y = a5*inv; v.z = a6*inv; v.w = a7*inv; }
        else    { v.x = a0*inv; v.y = a1*inv; v.z = a2*inv; v.w = a3*inv; }
        *(float4*)(out + (long)node * D + l16 * 8 + hi * 4) = v;
    }
}

extern "C" void kernel_launch(void* const* d_in, const int* in_sizes, int n_in,
                              void* d_out, int out_size, void* d_ws, size_t ws_size,
                              hipStream_t stream) {
    const float* inlayer  = (const float*)d_in[0];
    const float* dual     = (const float*)d_in[1];
    const float* conv_w   = (const float*)d_in[2];
    const float* conv_b   = (const float*)d_in[3];
    const int*   edge_idx = (const int*)d_in[4];   // [2, NNZ]: rows then cols
    const int*   edge_rel = (const int*)d_in[5];
    float* out = (float*)d_out;
    const int* rows = edge_idx;
    const int* cols = edge_idx + NNZ;

    // workspace layout (16B aligned) — total ~24.3 MB
    char* ws = (char*)d_ws;
    float*              exp_scores = (float*)             (ws);             // 4 KB
    float*              denom      = (float*)             (ws + 4096);      // 4 B
    unsigned*           bincur     = (unsigned*)          (ws + 8192);      // 98*16 u32 (line-padded)
    unsigned*           starts     = (unsigned*)          (ws + 16384);     // 50001 u32
    unsigned long long* binbuf     = (unsigned long long*)(ws + 217088);    // 98*10240*8 = 8.03 MB
    unsigned*           bpack      = (unsigned*)          (ws + 8245248);   // 3.2 MB
    __half2*            hinl       = (__half2*)           (ws + 11445248);  // 12.8 MB

    // zero denom + bincur in one ~10 KB fill
    hipMemsetAsync(ws + 4096, 0, 4096 + NBIN * 64, stream);

    k1_kernel<<<NCH, K1T, 0, stream>>>(rows, cols, edge_rel, dual, conv_w, conv_b,
                                       inlayer, exp_scores, bincur, binbuf, hinl);
    place_kernel<<<NBIN * 4, PBT, 0, stream>>>(bincur, binbuf, exp_scores,
                                               starts, bpack, denom);
    int grid = (N_NODES + 3) / 4;   // 4 waves/block, one node per wave
    gather_kernel<<<grid, 256, 0, stream>>>(starts, bpack, exp_scores,
                                            hinl, denom, out);
}